// Round 20
// baseline (217.438 us; speedup 1.0000x reference)
//
#include <hip/hip_runtime.h>

#define LEAF_SZ 32
#define MAXN 16384
#define MAXNODES 65536
#define ARENA_BASE 32768
#define MAXG 64
#define NQ 1024
#define BGRID 128
#define LCAP 256
#define LSTK 192
#define BSTK 96
#define WQCAP 256
#define NW0 16

struct __align__(64) TNode { int4 meta; float4 c4; float4 m4; float4 pad; };

// Static device scratch (fully rewritten each call; no cross-call state relied on).
__device__ int    g_perm[MAXN];
__device__ int    g_ptmp[MAXN];
__device__ float4 g_p4[MAXN];    // x,y,z,charge in perm order
__device__ float4 g_t4[MAXN];
__device__ int    g_nstart[MAXNODES];
__device__ int    g_nend[MAXNODES];
__device__ TNode  g_nodes[MAXNODES];
__device__ int    g_root[MAXG];
__device__ int    g_ncount;
__device__ int    g_lrange[4];

struct NodeSh {
    float  mn[4][3], mx[4][3];
    double sx[4], sy[4], sz[4], sq[4];
    int    c8[4][8];
    int    cur[8];
    float  cc[3];
    int    info;
    int    base, num;
    int    tot[8], offk[8];
};

// Block-cooperative node processing (R2-proven logic, 256 threads).
__device__ __forceinline__ void process_node2(NodeSh& sh, int n, int st, int en)
{
    const int tid  = threadIdx.x;
    const int wid  = tid >> 6;
    const int lane = tid & 63;
    const int cnt = en - st;

    float mnx = 3.402823466e38f, mny = mnx, mnz = mnx;
    float mxx = -mnx, mxy = -mnx, mxz = -mnx;
    double sx = 0.0, sy = 0.0, sz = 0.0, sq = 0.0;
    for (int j = st + tid; j < en; j += 256) {
        float4 p = g_p4[j];
        mnx = fminf(mnx, p.x); mny = fminf(mny, p.y); mnz = fminf(mnz, p.z);
        mxx = fmaxf(mxx, p.x); mxy = fmaxf(mxy, p.y); mxz = fmaxf(mxz, p.z);
        sx += (double)p.x; sy += (double)p.y; sz += (double)p.z; sq += (double)p.w;
    }
    for (int o = 1; o < 64; o <<= 1) {
        mnx = fminf(mnx, __shfl_xor(mnx, o));
        mny = fminf(mny, __shfl_xor(mny, o));
        mnz = fminf(mnz, __shfl_xor(mnz, o));
        mxx = fmaxf(mxx, __shfl_xor(mxx, o));
        mxy = fmaxf(mxy, __shfl_xor(mxy, o));
        mxz = fmaxf(mxz, __shfl_xor(mxz, o));
        sx += __shfl_xor(sx, o);
        sy += __shfl_xor(sy, o);
        sz += __shfl_xor(sz, o);
        sq += __shfl_xor(sq, o);
    }
    if (lane == 0) {
        sh.mn[wid][0] = mnx; sh.mn[wid][1] = mny; sh.mn[wid][2] = mnz;
        sh.mx[wid][0] = mxx; sh.mx[wid][1] = mxy; sh.mx[wid][2] = mxz;
        sh.sx[wid] = sx; sh.sy[wid] = sy; sh.sz[wid] = sz; sh.sq[wid] = sq;
    }
    __syncthreads();
    if (tid == 0) {
        float a0 = sh.mn[0][0], a1 = sh.mn[0][1], a2 = sh.mn[0][2];
        float b0 = sh.mx[0][0], b1 = sh.mx[0][1], b2 = sh.mx[0][2];
        double tx = sh.sx[0], ty = sh.sy[0], tz = sh.sz[0], tq = sh.sq[0];
        for (int w = 1; w < 4; ++w) {
            a0 = fminf(a0, sh.mn[w][0]); a1 = fminf(a1, sh.mn[w][1]); a2 = fminf(a2, sh.mn[w][2]);
            b0 = fmaxf(b0, sh.mx[w][0]); b1 = fmaxf(b1, sh.mx[w][1]); b2 = fmaxf(b2, sh.mx[w][2]);
            tx += sh.sx[w]; ty += sh.sy[w]; tz += sh.sz[w]; tq += sh.sq[w];
        }
        float cx = 0.5f * (a0 + b0), cy = 0.5f * (a1 + b1), cz = 0.5f * (a2 + b2);
        g_nodes[n].c4 = make_float4(cx, cy, cz, 0.5f * fmaxf(fmaxf(b0 - a0, b1 - a1), b2 - a2));
        const float fc = (float)cnt;
        g_nodes[n].m4 = make_float4((float)tx / fc, (float)ty / fc, (float)tz / fc, (float)tq);
        sh.cc[0] = cx; sh.cc[1] = cy; sh.cc[2] = cz;
        if (cnt <= LEAF_SZ) { g_nodes[n].meta = make_int4(st, en, 0, 0); sh.info = -1; }
        else sh.info = 0;
    }
    __syncthreads();
    if (sh.info < 0) return;
    const float cx = sh.cc[0], cy = sh.cc[1], cz = sh.cc[2];

    int c8[8] = {0,0,0,0,0,0,0,0};
    for (int j = st + tid; j < en; j += 256) {
        float4 p = g_p4[j];
        int oct = (p.x >= cx ? 1 : 0) | (p.y >= cy ? 2 : 0) | (p.z >= cz ? 4 : 0);
        c8[oct]++;
    }
    #pragma unroll
    for (int k = 0; k < 8; ++k)
        for (int o = 1; o < 64; o <<= 1)
            c8[k] += __shfl_xor(c8[k], o);
    if (lane == 0)
        #pragma unroll
        for (int k = 0; k < 8; ++k) sh.c8[wid][k] = c8[k];
    __syncthreads();
    if (tid == 0) {
        int tot[8], nonempty = 0;
        #pragma unroll
        for (int k = 0; k < 8; ++k) {
            tot[k] = sh.c8[0][k] + sh.c8[1][k] + sh.c8[2][k] + sh.c8[3][k];
            nonempty += (tot[k] > 0) ? 1 : 0;
        }
        if (nonempty <= 1) { g_nodes[n].meta = make_int4(st, en, 0, 0); sh.info = -1; }
        else {
            int base = atomicAdd(&g_ncount, nonempty);
            int acc = st, ci = base;
            #pragma unroll
            for (int k = 0; k < 8; ++k) {
                sh.cur[k] = acc;
                sh.offk[k] = acc - st;
                sh.tot[k] = tot[k];
                if (tot[k] > 0) { g_nstart[ci] = acc; g_nend[ci] = acc + tot[k]; ++ci; }
                acc += tot[k];
            }
            g_nodes[n].meta = make_int4(st, en, base, nonempty);
            sh.base = base; sh.num = nonempty; sh.info = 1;
        }
    }
    __syncthreads();
    if (sh.info < 0) return;

    for (int j = st + tid; j < en; j += 256) {
        float4 p = g_p4[j];
        int id = g_perm[j];
        int oct = (p.x >= cx ? 1 : 0) | (p.y >= cy ? 2 : 0) | (p.z >= cz ? 4 : 0);
        int pdst = atomicAdd(&sh.cur[oct], 1);
        g_ptmp[pdst] = id; g_t4[pdst] = p;
    }
    __syncthreads();
    for (int j = st + tid; j < en; j += 256) {
        g_perm[j] = g_ptmp[j];
        g_p4[j]   = g_t4[j];
    }
    __syncthreads();
}

// ---------------------------------------------------------------------------
// 1024-thread node processing for level-1 children inside level0: reads g_p4,
// FIXED child arena cb2 (8 slots, rank-consecutive; slots pre-set to -1).
// No global atomics at all.
// ---------------------------------------------------------------------------
__device__ __forceinline__ void process1024(
    int n, int st, int en, int cb2,
    float (*s_mn)[3], float (*s_mx)[3],
    double* s_sx, double* s_sy, double* s_sz, double* s_sq,
    int (*s_c8)[8], int* s_cur, float* s_cc, int* s_info)
{
    const int tid = threadIdx.x, wid = tid >> 6, lane = tid & 63;
    const int cnt = en - st;

    float mnx = 3.402823466e38f, mny = mnx, mnz = mnx;
    float mxx = -mnx, mxy = -mnx, mxz = -mnx;
    double sx = 0.0, sy = 0.0, sz = 0.0, sq = 0.0;
    for (int j = st + tid; j < en; j += 1024) {
        float4 p = g_p4[j];
        mnx = fminf(mnx, p.x); mny = fminf(mny, p.y); mnz = fminf(mnz, p.z);
        mxx = fmaxf(mxx, p.x); mxy = fmaxf(mxy, p.y); mxz = fmaxf(mxz, p.z);
        sx += (double)p.x; sy += (double)p.y; sz += (double)p.z; sq += (double)p.w;
    }
    for (int o = 1; o < 64; o <<= 1) {
        mnx = fminf(mnx, __shfl_xor(mnx, o));
        mny = fminf(mny, __shfl_xor(mny, o));
        mnz = fminf(mnz, __shfl_xor(mnz, o));
        mxx = fmaxf(mxx, __shfl_xor(mxx, o));
        mxy = fmaxf(mxy, __shfl_xor(mxy, o));
        mxz = fmaxf(mxz, __shfl_xor(mxz, o));
        sx += __shfl_xor(sx, o);
        sy += __shfl_xor(sy, o);
        sz += __shfl_xor(sz, o);
        sq += __shfl_xor(sq, o);
    }
    if (lane == 0) {
        s_mn[wid][0] = mnx; s_mn[wid][1] = mny; s_mn[wid][2] = mnz;
        s_mx[wid][0] = mxx; s_mx[wid][1] = mxy; s_mx[wid][2] = mxz;
        s_sx[wid] = sx; s_sy[wid] = sy; s_sz[wid] = sz; s_sq[wid] = sq;
    }
    __syncthreads();
    if (tid == 0) {
        float a0 = s_mn[0][0], a1 = s_mn[0][1], a2 = s_mn[0][2];
        float b0 = s_mx[0][0], b1 = s_mx[0][1], b2 = s_mx[0][2];
        double tx = s_sx[0], ty = s_sy[0], tz = s_sz[0], tq = s_sq[0];
        for (int w = 1; w < NW0; ++w) {
            a0 = fminf(a0, s_mn[w][0]); a1 = fminf(a1, s_mn[w][1]); a2 = fminf(a2, s_mn[w][2]);
            b0 = fmaxf(b0, s_mx[w][0]); b1 = fmaxf(b1, s_mx[w][1]); b2 = fmaxf(b2, s_mx[w][2]);
            tx += s_sx[w]; ty += s_sy[w]; tz += s_sz[w]; tq += s_sq[w];
        }
        float cx = 0.5f * (a0 + b0), cy = 0.5f * (a1 + b1), cz = 0.5f * (a2 + b2);
        g_nodes[n].c4 = make_float4(cx, cy, cz, 0.5f * fmaxf(fmaxf(b0 - a0, b1 - a1), b2 - a2));
        const float fc = (float)cnt;
        g_nodes[n].m4 = make_float4((float)tx / fc, (float)ty / fc, (float)tz / fc, (float)tq);
        s_cc[0] = cx; s_cc[1] = cy; s_cc[2] = cz;
        *s_info = (cnt <= LEAF_SZ) ? -1 : 0;
        if (*s_info < 0) g_nodes[n].meta = make_int4(st, en, 0, 0);
    }
    __syncthreads();
    if (*s_info < 0) return;
    const float cx = s_cc[0], cy = s_cc[1], cz = s_cc[2];

    int c8[8] = {0,0,0,0,0,0,0,0};
    for (int j = st + tid; j < en; j += 1024) {
        float4 p = g_p4[j];
        int oct = (p.x >= cx ? 1 : 0) | (p.y >= cy ? 2 : 0) | (p.z >= cz ? 4 : 0);
        c8[oct]++;
    }
    #pragma unroll
    for (int k = 0; k < 8; ++k)
        for (int o = 1; o < 64; o <<= 1)
            c8[k] += __shfl_xor(c8[k], o);
    if (lane == 0)
        #pragma unroll
        for (int k = 0; k < 8; ++k) s_c8[wid][k] = c8[k];
    __syncthreads();
    if (tid == 0) {
        int tot[8], nonempty = 0;
        #pragma unroll
        for (int k = 0; k < 8; ++k) {
            int tk = 0;
            for (int w = 0; w < NW0; ++w) tk += s_c8[w][k];
            tot[k] = tk;
            nonempty += (tk > 0) ? 1 : 0;
        }
        if (nonempty <= 1) {
            g_nodes[n].meta = make_int4(st, en, 0, 0);
            *s_info = -1;
        } else {
            int acc = st, ci = cb2;
            #pragma unroll
            for (int k = 0; k < 8; ++k) {
                s_cur[k] = acc;
                if (tot[k] > 0) { g_nstart[ci] = acc; g_nend[ci] = acc + tot[k]; ++ci; }
                acc += tot[k];
            }
            g_nodes[n].meta = make_int4(st, en, cb2, nonempty);
            *s_info = 1;
        }
    }
    __syncthreads();
    if (*s_info < 0) return;

    for (int j = st + tid; j < en; j += 1024) {
        float4 p = g_p4[j];
        int id = g_perm[j];
        int oct = (p.x >= cx ? 1 : 0) | (p.y >= cy ? 2 : 0) | (p.z >= cz ? 4 : 0);
        int pdst = atomicAdd(&s_cur[oct], 1);
        g_t4[pdst] = p; g_ptmp[pdst] = id;
    }
    __syncthreads();
    for (int j = st + tid; j < en; j += 1024) {
        g_p4[j]   = g_t4[j];
        g_perm[j] = g_ptmp[j];
    }
    __syncthreads();
}

// ---------------------------------------------------------------------------
// Fused init + level-0 + level-1: one 1024-thread block per graph. Root read
// directly from inputs; level-1 children processed sequentially at full block
// width via fixed level-2 arena (nb + g*64 + c*8; unused slots -1). Zero
// cross-block coordination inside the launch: g_ncount / g_lrange are written
// by block 0 and consumed only in the NEXT launch.
// ---------------------------------------------------------------------------
__global__ __launch_bounds__(1024)
void level0_kernel(const float* __restrict__ pos, const float* __restrict__ src,
                   const int* __restrict__ batch, int N, int n_graphs)
{
    __shared__ int    s_first[MAXG], s_end[MAXG];
    __shared__ float  s_mn[NW0][3], s_mx[NW0][3];
    __shared__ double s_sx[NW0], s_sy[NW0], s_sz[NW0], s_sq[NW0];
    __shared__ int    s_c8[NW0][8];
    __shared__ int    s_cur[8];
    __shared__ float  s_cc[3];
    __shared__ int    s_info;
    const int tid = threadIdx.x, wid = tid >> 6, lane = tid & 63;
    const int ng = (n_graphs < MAXG) ? n_graphs : MAXG;

    for (int g = tid; g < MAXG; g += 1024) { s_first[g] = -1; s_end[g] = 0; }
    __syncthreads();
    for (int i = tid; i < N; i += 1024) {
        int b = batch[i];
        if (i == 0     || batch[i-1] != b) s_first[b] = i;
        if (i == N - 1 || batch[i+1] != b) s_end[b]   = i + 1;
    }
    __syncthreads();

    const int g = blockIdx.x;
    int nc = 0, myroot = -1;
    for (int q = 0; q < ng; ++q)
        if (s_first[q] >= 0) { if (q == g) myroot = nc; ++nc; }
    const int nb    = nc + 8 * ng;     // level-1 arena end
    const int l2end = nb + 64 * ng;    // level-2 arena end

    if (g == 0 && tid == 0) {
        int r = 0;
        for (int q = 0; q < ng; ++q) {
            if (s_first[q] >= 0) g_root[q] = r++;
            else {
                g_root[q] = -1;
                for (int c = 0; c < 8;  ++c) g_nstart[nc + q*8  + c] = -1;  // dead L1 arena
                for (int c = 0; c < 64; ++c) g_nstart[nb + q*64 + c] = -1;  // dead L2 arena
            }
        }
        g_ncount    = l2end;           // alloc base for level-3+ (used next launch)
        g_lrange[1] = nb;              // level-2 task range [nb, l2end)
        g_lrange[2] = l2end;
    }
    if (g >= ng || myroot < 0) return;

    // init this graph's own level-2 arena slots
    for (int c = tid; c < 64; c += 1024) g_nstart[nb + g*64 + c] = -1;

    const int st = s_first[g], en = s_end[g];
    const int cnt = en - st;
    const int n = myroot;
    const int cbase = nc + g * 8;

    // ---- root: pass 1 (bbox + monopole, direct from inputs) ----
    float mnx = 3.402823466e38f, mny = mnx, mnz = mnx;
    float mxx = -mnx, mxy = -mnx, mxz = -mnx;
    double sx = 0.0, sy = 0.0, sz = 0.0, sq = 0.0;
    for (int j = st + tid; j < en; j += 1024) {
        float x = pos[3*j], y = pos[3*j+1], z = pos[3*j+2], s = src[j];
        mnx = fminf(mnx, x); mny = fminf(mny, y); mnz = fminf(mnz, z);
        mxx = fmaxf(mxx, x); mxy = fmaxf(mxy, y); mxz = fmaxf(mxz, z);
        sx += (double)x; sy += (double)y; sz += (double)z; sq += (double)s;
    }
    for (int o = 1; o < 64; o <<= 1) {
        mnx = fminf(mnx, __shfl_xor(mnx, o));
        mny = fminf(mny, __shfl_xor(mny, o));
        mnz = fminf(mnz, __shfl_xor(mnz, o));
        mxx = fmaxf(mxx, __shfl_xor(mxx, o));
        mxy = fmaxf(mxy, __shfl_xor(mxy, o));
        mxz = fmaxf(mxz, __shfl_xor(mxz, o));
        sx += __shfl_xor(sx, o);
        sy += __shfl_xor(sy, o);
        sz += __shfl_xor(sz, o);
        sq += __shfl_xor(sq, o);
    }
    if (lane == 0) {
        s_mn[wid][0] = mnx; s_mn[wid][1] = mny; s_mn[wid][2] = mnz;
        s_mx[wid][0] = mxx; s_mx[wid][1] = mxy; s_mx[wid][2] = mxz;
        s_sx[wid] = sx; s_sy[wid] = sy; s_sz[wid] = sz; s_sq[wid] = sq;
    }
    __syncthreads();
    if (tid == 0) {
        float a0 = s_mn[0][0], a1 = s_mn[0][1], a2 = s_mn[0][2];
        float b0 = s_mx[0][0], b1 = s_mx[0][1], b2 = s_mx[0][2];
        double tx = s_sx[0], ty = s_sy[0], tz = s_sz[0], tq = s_sq[0];
        for (int w = 1; w < NW0; ++w) {
            a0 = fminf(a0, s_mn[w][0]); a1 = fminf(a1, s_mn[w][1]); a2 = fminf(a2, s_mn[w][2]);
            b0 = fmaxf(b0, s_mx[w][0]); b1 = fmaxf(b1, s_mx[w][1]); b2 = fmaxf(b2, s_mx[w][2]);
            tx += s_sx[w]; ty += s_sy[w]; tz += s_sz[w]; tq += s_sq[w];
        }
        float cx = 0.5f * (a0 + b0), cy = 0.5f * (a1 + b1), cz = 0.5f * (a2 + b2);
        g_nodes[n].c4 = make_float4(cx, cy, cz, 0.5f * fmaxf(fmaxf(b0 - a0, b1 - a1), b2 - a2));
        const float fc = (float)cnt;
        g_nodes[n].m4 = make_float4((float)tx / fc, (float)ty / fc, (float)tz / fc, (float)tq);
        s_cc[0] = cx; s_cc[1] = cy; s_cc[2] = cz;
        s_info = (cnt <= LEAF_SZ) ? -1 : 0;
        if (s_info < 0) g_nodes[n].meta = make_int4(st, en, 0, 0);
    }
    __syncthreads();

    if (s_info == 0) {
        // root pass 2: octant counts
        const float cx = s_cc[0], cy = s_cc[1], cz = s_cc[2];
        int c8[8] = {0,0,0,0,0,0,0,0};
        for (int j = st + tid; j < en; j += 1024) {
            int oct = (pos[3*j] >= cx ? 1 : 0) | (pos[3*j+1] >= cy ? 2 : 0) | (pos[3*j+2] >= cz ? 4 : 0);
            c8[oct]++;
        }
        #pragma unroll
        for (int k = 0; k < 8; ++k)
            for (int o = 1; o < 64; o <<= 1)
                c8[k] += __shfl_xor(c8[k], o);
        if (lane == 0)
            #pragma unroll
            for (int k = 0; k < 8; ++k) s_c8[wid][k] = c8[k];
        __syncthreads();
        if (tid == 0) {
            int tot[8], nonempty = 0;
            #pragma unroll
            for (int k = 0; k < 8; ++k) {
                int tk = 0;
                for (int w = 0; w < NW0; ++w) tk += s_c8[w][k];
                tot[k] = tk;
                nonempty += (tk > 0) ? 1 : 0;
            }
            if (nonempty <= 1) {
                g_nodes[n].meta = make_int4(st, en, 0, 0);
                for (int c = 0; c < 8; ++c) g_nstart[cbase + c] = -1;
                s_info = -1;
            } else {
                int acc = st, ci = cbase;
                #pragma unroll
                for (int k = 0; k < 8; ++k) {
                    s_cur[k] = acc;
                    if (tot[k] > 0) { g_nstart[ci] = acc; g_nend[ci] = acc + tot[k]; ++ci; }
                    acc += tot[k];
                }
                for (int c = ci; c < cbase + 8; ++c) g_nstart[c] = -1;
                g_nodes[n].meta = make_int4(st, en, cbase, nonempty);
                s_info = 1;
            }
        }
        __syncthreads();
    } else if (tid == 0) {
        for (int c = 0; c < 8; ++c) g_nstart[cbase + c] = -1;
    }

    if (s_info == 1) {
        // root pass 3: scatter directly from inputs into permuted g_p4/g_perm
        const float cx = s_cc[0], cy = s_cc[1], cz = s_cc[2];
        for (int j = st + tid; j < en; j += 1024) {
            float x = pos[3*j], y = pos[3*j+1], z = pos[3*j+2], s = src[j];
            int oct = (x >= cx ? 1 : 0) | (y >= cy ? 2 : 0) | (z >= cz ? 4 : 0);
            int pdst = atomicAdd(&s_cur[oct], 1);
            g_p4[pdst] = make_float4(x, y, z, s);
            g_perm[pdst] = j;
        }
    } else {
        for (int j = st + tid; j < en; j += 1024) {
            g_p4[j] = make_float4(pos[3*j], pos[3*j+1], pos[3*j+2], src[j]);
            g_perm[j] = j;
        }
    }
    __syncthreads();

    // ---- level-1 children, sequential, full 1024-thread block each ----
    for (int c = 0; c < 8; ++c) {
        int cn  = cbase + c;
        int cst = g_nstart[cn];               // block-uniform global read
        if (cst < 0) continue;
        process1024(cn, cst, g_nend[cn], nb + g*64 + c*8,
                    s_mn, s_mx, s_sx, s_sy, s_sz, s_sq, s_c8, s_cur, s_cc, &s_info);
    }
}

// ---------------------------------------------------------------------------
// LDS-resident subtree DFS (cnt <= LCAP) — R11-proven, AoS node writes.
// ---------------------------------------------------------------------------
__device__ __forceinline__ void lds_subtree(int rootn, int st, int en, int abase,
                                            float4* a4, int* aid,
                                            int* lid, int* la, int* lbb)
{
    const int lane = threadIdx.x & 63;
    const int cnt = en - st;
    const unsigned long long mlt = (1ull << lane) - 1ull;

    for (int j = lane; j < cnt; j += 64) {
        a4[j]  = g_p4[st + j];
        aid[j] = g_perm[st + j];
    }
    asm volatile("s_waitcnt vmcnt(0) lgkmcnt(0)" ::: "memory");
    __builtin_amdgcn_wave_barrier();

    int sp = 0;
    int cn = rootn, ca = 0, cb = cnt;
    while (true) {
        const int c = cb - ca;
        float4 pv[4]; int idv[4]; int oc[4];
        float mnx = 3.402823466e38f, mny = mnx, mnz = mnx;
        float mxx = -mnx, mxy = -mnx, mxz = -mnx;
        float sx = 0.f, sy = 0.f, sz = 0.f, sq = 0.f;
        #pragma unroll
        for (int i = 0; i < 4; ++i) {
            bool act = (i*64 + lane) < c;
            int j = act ? (ca + i*64 + lane) : ca;
            float4 p = a4[j];
            pv[i] = p; idv[i] = aid[j];
            if (act) {
                mnx = fminf(mnx, p.x); mny = fminf(mny, p.y); mnz = fminf(mnz, p.z);
                mxx = fmaxf(mxx, p.x); mxy = fmaxf(mxy, p.y); mxz = fmaxf(mxz, p.z);
                sx += p.x; sy += p.y; sz += p.z; sq += p.w;
            }
        }
        for (int o = 1; o < 64; o <<= 1) {
            mnx = fminf(mnx, __shfl_xor(mnx, o));
            mny = fminf(mny, __shfl_xor(mny, o));
            mnz = fminf(mnz, __shfl_xor(mnz, o));
            mxx = fmaxf(mxx, __shfl_xor(mxx, o));
            mxy = fmaxf(mxy, __shfl_xor(mxy, o));
            mxz = fmaxf(mxz, __shfl_xor(mxz, o));
            sx += __shfl_xor(sx, o);
            sy += __shfl_xor(sy, o);
            sz += __shfl_xor(sz, o);
            sq += __shfl_xor(sq, o);
        }
        const float cx = 0.5f * (mnx + mxx);
        const float cy = 0.5f * (mny + mxy);
        const float cz = 0.5f * (mnz + mxz);
        if (lane == 0) {
            g_nodes[cn].c4 = make_float4(cx, cy, cz, 0.5f * fmaxf(fmaxf(mxx - mnx, mxy - mny), mxz - mnz));
            const float fc = (float)c;
            g_nodes[cn].m4 = make_float4(sx / fc, sy / fc, sz / fc, sq);
        }

        int nonempty = 0;
        int c8[8] = {0,0,0,0,0,0,0,0};
        if (c > LEAF_SZ) {
            #pragma unroll
            for (int i = 0; i < 4; ++i) {
                bool act = (i*64 + lane) < c;
                int o = act ? ((pv[i].x >= cx ? 1 : 0) | (pv[i].y >= cy ? 2 : 0) | (pv[i].z >= cz ? 4 : 0)) : 8;
                oc[i] = o;
                #pragma unroll
                for (int k = 0; k < 8; ++k)
                    c8[k] += (int)__popcll(__ballot(o == k));
            }
            #pragma unroll
            for (int k = 0; k < 8; ++k) nonempty += (c8[k] > 0) ? 1 : 0;
        }

        if (c <= LEAF_SZ || nonempty <= 1) {
            if (lane == 0) g_nodes[cn].meta = make_int4(st + ca, st + cb, 0, 0);
        } else {
            int off[8], acc = 0;
            #pragma unroll
            for (int k = 0; k < 8; ++k) { off[k] = acc; acc += c8[k]; }
            if (lane == 0) g_nodes[cn].meta = make_int4(st + ca, st + cb, abase, nonempty);
            int cum[8] = {0,0,0,0,0,0,0,0};
            #pragma unroll
            for (int i = 0; i < 4; ++i) {
                int o = oc[i];
                int pdst = 0;
                #pragma unroll
                for (int k = 0; k < 8; ++k) {
                    unsigned long long b = __ballot(o == k);
                    if (o == k) pdst = ca + off[k] + cum[k] + (int)__popcll(b & mlt);
                    cum[k] += (int)__popcll(b);
                }
                if (o < 8) { a4[pdst] = pv[i]; aid[pdst] = idv[i]; }
            }
            asm volatile("s_waitcnt lgkmcnt(0)" ::: "memory");
            __builtin_amdgcn_wave_barrier();
            if (lane == 0) {
                int ci = 0;
                #pragma unroll
                for (int k = 0; k < 8; ++k) {
                    if (c8[k] > 0) {
                        lid[sp + ci] = abase + ci;
                        la [sp + ci] = ca + off[k];
                        lbb[sp + ci] = ca + off[k] + c8[k];
                        ++ci;
                    }
                }
            }
            abase += nonempty; sp += nonempty;
            if (sp > LSTK) sp = LSTK;
        }
        if (sp <= 0) break;
        --sp;
        __builtin_amdgcn_wave_barrier();
        asm volatile("s_waitcnt lgkmcnt(0)" ::: "memory");
        cn = lid[sp]; ca = la[sp]; cb = lbb[sp];
        __builtin_amdgcn_wave_barrier();
    }

    for (int j = lane; j < cnt; j += 64) {
        g_p4[st + j]  = a4[j];
        g_perm[st + j] = aid[j];
    }
    asm volatile("s_waitcnt vmcnt(0)" ::: "memory");
}

// ---------------------------------------------------------------------------
// Level-2+ build: tasks = fixed level-2 arena [lrange1, lrange2), -1 skipped.
// Phase 1: block-coop DFS over >LCAP nodes; phase 2: waves drain small
// subtrees. If wq is full, small nodes take the block-coop path (never lost).
// ---------------------------------------------------------------------------
__global__ __launch_bounds__(256) void block_subtree_kernel()
{
    __shared__ NodeSh sh;
    __shared__ int bs_id[BSTK], bs_st[BSTK], bs_en[BSTK];
    __shared__ int wq_id[WQCAP], wq_st[WQCAP], wq_en[WQCAP];
    __shared__ int s_bsp, s_wq;
    __shared__ float4 s_a4[4][LCAP];
    __shared__ int    s_aid[4][LCAP];
    __shared__ int    s_lid[4][LSTK], s_la[4][LSTK], s_lb[4][LSTK];

    const int tid = threadIdx.x;
    const int wid = tid >> 6;
    const int lb = g_lrange[1], le = g_lrange[2];

    for (int task = lb + blockIdx.x; task < le; task += BGRID) {
        __syncthreads();
        int tst = g_nstart[task];
        if (tst < 0) continue;                        // dead arena slot (block-uniform)
        if (tid == 0) {
            int en = g_nend[task];
            if (en - tst <= LCAP) { wq_id[0] = task; wq_st[0] = tst; wq_en[0] = en; s_wq = 1; s_bsp = 0; }
            else                  { bs_id[0] = task; bs_st[0] = tst; bs_en[0] = en; s_bsp = 1; s_wq = 0; }
        }
        __syncthreads();

        while (true) {
            __syncthreads();
            const int bsp = s_bsp;
            if (bsp == 0) break;
            const int n  = bs_id[bsp-1];
            const int st = bs_st[bsp-1];
            const int en = bs_en[bsp-1];
            __syncthreads();
            if (tid == 0) s_bsp = bsp - 1;
            process_node2(sh, n, st, en);
            if (tid == 0 && sh.info == 1) {
                int ci = 0;
                #pragma unroll
                for (int k = 0; k < 8; ++k) {
                    if (sh.tot[k] > 0) {
                        int cst = st + sh.offk[k], cen = cst + sh.tot[k];
                        int cid = sh.base + ci; ++ci;
                        if (cen - cst <= LCAP && s_wq < WQCAP) {
                            wq_id[s_wq] = cid; wq_st[s_wq] = cst; wq_en[s_wq] = cen; ++s_wq;
                        } else if (s_bsp < BSTK) {
                            bs_id[s_bsp] = cid; bs_st[s_bsp] = cst; bs_en[s_bsp] = cen; ++s_bsp;
                        }
                    }
                }
            }
        }
        __syncthreads();

        const int nwq = s_wq;
        float4* a4 = s_a4[wid];  int* aid = s_aid[wid];
        int* lid = s_lid[wid];   int* la = s_la[wid];  int* lbb = s_lb[wid];
        for (int i = wid; i < nwq; i += 4) {
            int cid = wq_id[i], cst = wq_st[i], cen = wq_en[i];
            lds_subtree(cid, cst, cen, ARENA_BASE + 2 * cst, a4, aid, lid, la, lbb);
        }
    }
}

// ---------------------------------------------------------------------------
// Traverse (R15-proven verbatim): 4 waves/block, one target per wave, static
// perm-order assignment (L1 sharing); scan-based chunked pair drain.
// ---------------------------------------------------------------------------
__global__ __launch_bounds__(256)
void traverse_kernel(const int* __restrict__ batch,
                     const float* __restrict__ p_scr, const float* __restrict__ p_soft,
                     float* __restrict__ out, int N)
{
    __shared__ int s_q[4][NQ];
    __shared__ int s_sb[4][64], s_ss[4][64], s_mk[4][64];
    __shared__ int s_qt[4];
    const int wid  = threadIdx.x >> 6;
    const int lane = threadIdx.x & 63;
    const int slot = blockIdx.x * 4 + wid;
    if (slot >= N) return;                 // wave-uniform; no __syncthreads used
    const int t = g_perm[slot];

    const float scr   = p_scr[0];
    const float soft  = p_soft[0];
    const float soft2 = soft * soft;
    const float cexp  = -scr * 1.4426950408889634f;  // exp(-scr*r) = exp2(cexp*r)
    const float4 tp = g_p4[slot];
    const float tx = tp.x, ty = tp.y, tz = tp.z;
    const int inv_t = slot;

    volatile int* q = s_q[wid];
    int* sb = s_sb[wid];
    int* ss = s_ss[wid];
    int* mk = s_mk[wid];
    if (lane == 0) { q[0] = g_root[batch[t]]; s_qt[wid] = 1; }
    __builtin_amdgcn_wave_barrier();

    float phi = 0.f;
    int qh = 0;
    while (true) {
        __builtin_amdgcn_wave_barrier();
        int qt = ((volatile int*)s_qt)[wid];
        if (qh >= qt) break;
        int take = qt - qh; if (take > 64) take = 64;
        int node = (lane < take) ? q[(qh + lane) & (NQ - 1)] : -1;
        qh += take;

        int leaf_st = 0, leaf_cnt = 0;
        if (node >= 0) {
            const int4 meta = g_nodes[node].meta;
            if (meta.w == 0) {
                leaf_st = meta.x; leaf_cnt = meta.y - meta.x;
            } else {
                float4 c4 = g_nodes[node].c4;
                float dx = tx - c4.x, dy = ty - c4.y, dz = tz - c4.z;
                float dist = sqrtf(dx*dx + dy*dy + dz*dz + soft2);
                float diam = fmaxf(2.0f * c4.w, 1e-9f);
                bool inside = (inv_t >= meta.x) && (inv_t < meta.y);
                if (!inside && diam < 0.5f * dist) {
                    float4 m4 = g_nodes[node].m4;
                    float ax = tx - m4.x, ay = ty - m4.y, az = tz - m4.z;
                    float s = ax*ax + ay*ay + az*az + soft2;
                    float rinv = rsqrtf(s);
                    phi += m4.w * exp2f(cexp * (s * rinv)) * rinv;
                } else {
                    int p = atomicAdd(&s_qt[wid], meta.w);
                    for (int c = 0; c < meta.w; ++c) q[(p + c) & (NQ - 1)] = meta.z + c;
                }
            }
        }

        // prefix-sum of (leaf size minus self)
        bool hasself = (inv_t >= leaf_st) && (inv_t < leaf_st + leaf_cnt);
        int cnt_adj = leaf_cnt - (hasself ? 1 : 0);
        int x = cnt_adj;
        #pragma unroll
        for (int o = 1; o < 64; o <<= 1) { int y = __shfl_up(x, o); if (lane >= o) x += y; }
        int total = __shfl(x, 63);
        int off = x - cnt_adj;

        if (total > 0) {
            sb[lane] = leaf_st - off;
            ss[lane] = hasself ? (off + (inv_t - leaf_st)) : 0x7fffffff;
            asm volatile("s_waitcnt lgkmcnt(0)" ::: "memory");
            __builtin_amdgcn_wave_barrier();
            int carry = -1;
            for (int cb = 0; cb < total; cb += 64) {
                mk[lane] = -1;
                asm volatile("s_waitcnt lgkmcnt(0)" ::: "memory");
                __builtin_amdgcn_wave_barrier();
                if (cnt_adj > 0 && off >= cb && off < cb + 64) mk[off - cb] = lane;
                asm volatile("s_waitcnt lgkmcnt(0)" ::: "memory");
                __builtin_amdgcn_wave_barrier();
                int own = mk[lane];
                if (lane == 0) own = own > carry ? own : carry;
                #pragma unroll
                for (int o = 1; o < 64; o <<= 1) {
                    int y = __shfl_up(own, o);
                    if (lane >= o) own = own > y ? own : y;
                }
                carry = __shfl(own, 63);
                int p = cb + lane;
                if (p < total) {
                    int j = sb[own] + p + ((p >= ss[own]) ? 1 : 0);
                    float4 pp = g_p4[j];
                    float dx = tx - pp.x, dy = ty - pp.y, dz = tz - pp.z;
                    float s = dx*dx + dy*dy + dz*dz + soft2;
                    float rinv = rsqrtf(s);
                    phi += pp.w * exp2f(cexp * (s * rinv)) * rinv;
                }
                __builtin_amdgcn_wave_barrier();
            }
        }
    }

    #pragma unroll
    for (int o = 1; o < 64; o <<= 1) phi += __shfl_xor(phi, o);
    if (lane == 0) out[t] = 0.5f * (tp.w * phi);
}

extern "C" void kernel_launch(void* const* d_in, const int* in_sizes, int n_in,
                              void* d_out, int out_size, void* d_ws, size_t ws_size,
                              hipStream_t stream) {
    const float* pos    = (const float*)d_in[0];
    const int*   batch  = (const int*)  d_in[1];
    const float* source = (const float*)d_in[3];
    const float* p_scr  = (const float*)d_in[4];
    const float* p_soft = (const float*)d_in[5];

    const int N        = in_sizes[0] / 3;
    const int n_graphs = in_sizes[2] / 9;

    int g0 = n_graphs > 0 ? n_graphs : 1;
    if (g0 > MAXG) g0 = MAXG;
    level0_kernel<<<g0, 1024, 0, stream>>>(pos, source, batch, N, n_graphs);
    block_subtree_kernel<<<BGRID, 256, 0, stream>>>();

    const int blocks = (N + 3) / 4;  // 4 waves (targets) per 256-thread block
    traverse_kernel<<<blocks, 256, 0, stream>>>(batch, p_scr, p_soft, (float*)d_out, N);
}

// Round 21
// 146.372 us; speedup vs baseline: 1.4855x; 1.4855x over previous
//
#include <hip/hip_runtime.h>

#define LEAF_SZ 32
#define MAXN 16384
#define MAXNODES 65536
#define ARENA_BASE 32768
#define MAXG 64
#define NQ 1024
#define BGRID 128
#define LCAP 256
#define LSTK 192
#define BSTK 32
#define WQCAP 64
#define NW0 16

struct __align__(64) TNode { int4 meta; float4 c4; float4 m4; float4 pad; };

// Static device scratch (fully rewritten each call; no cross-call state relied on).
__device__ int    g_perm[MAXN];
__device__ int    g_ptmp[MAXN];
__device__ float4 g_p4[MAXN];    // x,y,z,charge in perm order
__device__ float4 g_t4[MAXN];
__device__ int    g_nstart[MAXNODES];
__device__ int    g_nend[MAXNODES];
__device__ TNode  g_nodes[MAXNODES];
__device__ int    g_root[MAXG];
__device__ int    g_ncount;
__device__ int    g_lrange[4];
__device__ int    g_done[2];

struct NodeSh {
    float  mn[4][3], mx[4][3];
    double sx[4], sy[4], sz[4], sq[4];
    int    c8[4][8];
    int    cur[8];
    float  cc[3];
    int    info;
    int    base, num;
    int    tot[8], offk[8];
};

// Block-cooperative node processing (R2-proven logic, 256 threads).
__device__ __forceinline__ void process_node2(NodeSh& sh, int n, int st, int en)
{
    const int tid  = threadIdx.x;
    const int wid  = tid >> 6;
    const int lane = tid & 63;
    const int cnt = en - st;

    float mnx = 3.402823466e38f, mny = mnx, mnz = mnx;
    float mxx = -mnx, mxy = -mnx, mxz = -mnx;
    double sx = 0.0, sy = 0.0, sz = 0.0, sq = 0.0;
    for (int j = st + tid; j < en; j += 256) {
        float4 p = g_p4[j];
        mnx = fminf(mnx, p.x); mny = fminf(mny, p.y); mnz = fminf(mnz, p.z);
        mxx = fmaxf(mxx, p.x); mxy = fmaxf(mxy, p.y); mxz = fmaxf(mxz, p.z);
        sx += (double)p.x; sy += (double)p.y; sz += (double)p.z; sq += (double)p.w;
    }
    for (int o = 1; o < 64; o <<= 1) {
        mnx = fminf(mnx, __shfl_xor(mnx, o));
        mny = fminf(mny, __shfl_xor(mny, o));
        mnz = fminf(mnz, __shfl_xor(mnz, o));
        mxx = fmaxf(mxx, __shfl_xor(mxx, o));
        mxy = fmaxf(mxy, __shfl_xor(mxy, o));
        mxz = fmaxf(mxz, __shfl_xor(mxz, o));
        sx += __shfl_xor(sx, o);
        sy += __shfl_xor(sy, o);
        sz += __shfl_xor(sz, o);
        sq += __shfl_xor(sq, o);
    }
    if (lane == 0) {
        sh.mn[wid][0] = mnx; sh.mn[wid][1] = mny; sh.mn[wid][2] = mnz;
        sh.mx[wid][0] = mxx; sh.mx[wid][1] = mxy; sh.mx[wid][2] = mxz;
        sh.sx[wid] = sx; sh.sy[wid] = sy; sh.sz[wid] = sz; sh.sq[wid] = sq;
    }
    __syncthreads();
    if (tid == 0) {
        float a0 = sh.mn[0][0], a1 = sh.mn[0][1], a2 = sh.mn[0][2];
        float b0 = sh.mx[0][0], b1 = sh.mx[0][1], b2 = sh.mx[0][2];
        double tx = sh.sx[0], ty = sh.sy[0], tz = sh.sz[0], tq = sh.sq[0];
        for (int w = 1; w < 4; ++w) {
            a0 = fminf(a0, sh.mn[w][0]); a1 = fminf(a1, sh.mn[w][1]); a2 = fminf(a2, sh.mn[w][2]);
            b0 = fmaxf(b0, sh.mx[w][0]); b1 = fmaxf(b1, sh.mx[w][1]); b2 = fmaxf(b2, sh.mx[w][2]);
            tx += sh.sx[w]; ty += sh.sy[w]; tz += sh.sz[w]; tq += sh.sq[w];
        }
        float cx = 0.5f * (a0 + b0), cy = 0.5f * (a1 + b1), cz = 0.5f * (a2 + b2);
        g_nodes[n].c4 = make_float4(cx, cy, cz, 0.5f * fmaxf(fmaxf(b0 - a0, b1 - a1), b2 - a2));
        const float fc = (float)cnt;
        g_nodes[n].m4 = make_float4((float)tx / fc, (float)ty / fc, (float)tz / fc, (float)tq);
        sh.cc[0] = cx; sh.cc[1] = cy; sh.cc[2] = cz;
        if (cnt <= LEAF_SZ) { g_nodes[n].meta = make_int4(st, en, 0, 0); sh.info = -1; }
        else sh.info = 0;
    }
    __syncthreads();
    if (sh.info < 0) return;
    const float cx = sh.cc[0], cy = sh.cc[1], cz = sh.cc[2];

    int c8[8] = {0,0,0,0,0,0,0,0};
    for (int j = st + tid; j < en; j += 256) {
        float4 p = g_p4[j];
        int oct = (p.x >= cx ? 1 : 0) | (p.y >= cy ? 2 : 0) | (p.z >= cz ? 4 : 0);
        c8[oct]++;
    }
    #pragma unroll
    for (int k = 0; k < 8; ++k)
        for (int o = 1; o < 64; o <<= 1)
            c8[k] += __shfl_xor(c8[k], o);
    if (lane == 0)
        #pragma unroll
        for (int k = 0; k < 8; ++k) sh.c8[wid][k] = c8[k];
    __syncthreads();
    if (tid == 0) {
        int tot[8], nonempty = 0;
        #pragma unroll
        for (int k = 0; k < 8; ++k) {
            tot[k] = sh.c8[0][k] + sh.c8[1][k] + sh.c8[2][k] + sh.c8[3][k];
            nonempty += (tot[k] > 0) ? 1 : 0;
        }
        if (nonempty <= 1) { g_nodes[n].meta = make_int4(st, en, 0, 0); sh.info = -1; }
        else {
            int base = atomicAdd(&g_ncount, nonempty);
            int acc = st, ci = base;
            #pragma unroll
            for (int k = 0; k < 8; ++k) {
                sh.cur[k] = acc;
                sh.offk[k] = acc - st;
                sh.tot[k] = tot[k];
                if (tot[k] > 0) { g_nstart[ci] = acc; g_nend[ci] = acc + tot[k]; ++ci; }
                acc += tot[k];
            }
            g_nodes[n].meta = make_int4(st, en, base, nonempty);
            sh.base = base; sh.num = nonempty; sh.info = 1;
        }
    }
    __syncthreads();
    if (sh.info < 0) return;

    for (int j = st + tid; j < en; j += 256) {
        float4 p = g_p4[j];
        int id = g_perm[j];
        int oct = (p.x >= cx ? 1 : 0) | (p.y >= cy ? 2 : 0) | (p.z >= cz ? 4 : 0);
        int pdst = atomicAdd(&sh.cur[oct], 1);
        g_ptmp[pdst] = id; g_t4[pdst] = p;
    }
    __syncthreads();
    for (int j = st + tid; j < en; j += 256) {
        g_perm[j] = g_ptmp[j];
        g_p4[j]   = g_t4[j];
    }
    __syncthreads();
}

// ---------------------------------------------------------------------------
// Fused init + level-0 (R15-proven): one 1024-thread block per graph, reading
// inputs directly; fixed child arena (nc + g*8, unused slots -1).
// ---------------------------------------------------------------------------
__global__ __launch_bounds__(1024)
void level0_kernel(const float* __restrict__ pos, const float* __restrict__ src,
                   const int* __restrict__ batch, int N, int n_graphs)
{
    __shared__ int    s_first[MAXG], s_end[MAXG];
    __shared__ float  s_mn[NW0][3], s_mx[NW0][3];
    __shared__ double s_sx[NW0], s_sy[NW0], s_sz[NW0], s_sq[NW0];
    __shared__ int    s_c8[NW0][8];
    __shared__ int    s_cur[8];
    __shared__ float  s_cc[3];
    __shared__ int    s_info;
    const int tid = threadIdx.x, wid = tid >> 6, lane = tid & 63;
    const int ng = (n_graphs < MAXG) ? n_graphs : MAXG;

    for (int g = tid; g < MAXG; g += 1024) { s_first[g] = -1; s_end[g] = 0; }
    __syncthreads();
    for (int i = tid; i < N; i += 1024) {
        int b = batch[i];
        if (i == 0     || batch[i-1] != b) s_first[b] = i;
        if (i == N - 1 || batch[i+1] != b) s_end[b]   = i + 1;
    }
    __syncthreads();

    const int g = blockIdx.x;
    int nc = 0, myroot = -1;
    for (int q = 0; q < ng; ++q)
        if (s_first[q] >= 0) { if (q == g) myroot = nc; ++nc; }
    const int nb = nc + 8 * ng;

    if (g == 0 && tid == 0) {
        int r = 0;
        for (int q = 0; q < ng; ++q) {
            if (s_first[q] >= 0) g_root[q] = r++;
            else {
                g_root[q] = -1;
                for (int c = 0; c < 8; ++c) g_nstart[nc + q*8 + c] = -1;  // dead arena
            }
        }
        g_ncount = nb;
        g_lrange[0] = nc;
        g_lrange[1] = nb;
        g_done[1] = 0;
    }
    if (g >= ng || myroot < 0) return;

    const int st = s_first[g], en = s_end[g];
    const int cnt = en - st;
    const int n = myroot;
    const int cbase = nc + g * 8;

    float mnx = 3.402823466e38f, mny = mnx, mnz = mnx;
    float mxx = -mnx, mxy = -mnx, mxz = -mnx;
    double sx = 0.0, sy = 0.0, sz = 0.0, sq = 0.0;
    for (int j = st + tid; j < en; j += 1024) {
        float x = pos[3*j], y = pos[3*j+1], z = pos[3*j+2], s = src[j];
        mnx = fminf(mnx, x); mny = fminf(mny, y); mnz = fminf(mnz, z);
        mxx = fmaxf(mxx, x); mxy = fmaxf(mxy, y); mxz = fmaxf(mxz, z);
        sx += (double)x; sy += (double)y; sz += (double)z; sq += (double)s;
    }
    for (int o = 1; o < 64; o <<= 1) {
        mnx = fminf(mnx, __shfl_xor(mnx, o));
        mny = fminf(mny, __shfl_xor(mny, o));
        mnz = fminf(mnz, __shfl_xor(mnz, o));
        mxx = fmaxf(mxx, __shfl_xor(mxx, o));
        mxy = fmaxf(mxy, __shfl_xor(mxy, o));
        mxz = fmaxf(mxz, __shfl_xor(mxz, o));
        sx += __shfl_xor(sx, o);
        sy += __shfl_xor(sy, o);
        sz += __shfl_xor(sz, o);
        sq += __shfl_xor(sq, o);
    }
    if (lane == 0) {
        s_mn[wid][0] = mnx; s_mn[wid][1] = mny; s_mn[wid][2] = mnz;
        s_mx[wid][0] = mxx; s_mx[wid][1] = mxy; s_mx[wid][2] = mxz;
        s_sx[wid] = sx; s_sy[wid] = sy; s_sz[wid] = sz; s_sq[wid] = sq;
    }
    __syncthreads();
    if (tid == 0) {
        float a0 = s_mn[0][0], a1 = s_mn[0][1], a2 = s_mn[0][2];
        float b0 = s_mx[0][0], b1 = s_mx[0][1], b2 = s_mx[0][2];
        double tx = s_sx[0], ty = s_sy[0], tz = s_sz[0], tq = s_sq[0];
        for (int w = 1; w < NW0; ++w) {
            a0 = fminf(a0, s_mn[w][0]); a1 = fminf(a1, s_mn[w][1]); a2 = fminf(a2, s_mn[w][2]);
            b0 = fmaxf(b0, s_mx[w][0]); b1 = fmaxf(b1, s_mx[w][1]); b2 = fmaxf(b2, s_mx[w][2]);
            tx += s_sx[w]; ty += s_sy[w]; tz += s_sz[w]; tq += s_sq[w];
        }
        float cx = 0.5f * (a0 + b0), cy = 0.5f * (a1 + b1), cz = 0.5f * (a2 + b2);
        g_nodes[n].c4 = make_float4(cx, cy, cz, 0.5f * fmaxf(fmaxf(b0 - a0, b1 - a1), b2 - a2));
        const float fc = (float)cnt;
        g_nodes[n].m4 = make_float4((float)tx / fc, (float)ty / fc, (float)tz / fc, (float)tq);
        s_cc[0] = cx; s_cc[1] = cy; s_cc[2] = cz;
        s_info = (cnt <= LEAF_SZ) ? -1 : 0;
        if (s_info < 0) g_nodes[n].meta = make_int4(st, en, 0, 0);
    }
    __syncthreads();

    if (s_info == 0) {
        const float cx = s_cc[0], cy = s_cc[1], cz = s_cc[2];
        int c8[8] = {0,0,0,0,0,0,0,0};
        for (int j = st + tid; j < en; j += 1024) {
            int oct = (pos[3*j] >= cx ? 1 : 0) | (pos[3*j+1] >= cy ? 2 : 0) | (pos[3*j+2] >= cz ? 4 : 0);
            c8[oct]++;
        }
        #pragma unroll
        for (int k = 0; k < 8; ++k)
            for (int o = 1; o < 64; o <<= 1)
                c8[k] += __shfl_xor(c8[k], o);
        if (lane == 0)
            #pragma unroll
            for (int k = 0; k < 8; ++k) s_c8[wid][k] = c8[k];
        __syncthreads();
        if (tid == 0) {
            int tot[8], nonempty = 0;
            #pragma unroll
            for (int k = 0; k < 8; ++k) {
                int tk = 0;
                for (int w = 0; w < NW0; ++w) tk += s_c8[w][k];
                tot[k] = tk;
                nonempty += (tk > 0) ? 1 : 0;
            }
            if (nonempty <= 1) {
                g_nodes[n].meta = make_int4(st, en, 0, 0);
                for (int c = 0; c < 8; ++c) g_nstart[cbase + c] = -1;
                s_info = -1;
            } else {
                int acc = st, ci = cbase;
                #pragma unroll
                for (int k = 0; k < 8; ++k) {
                    s_cur[k] = acc;
                    if (tot[k] > 0) { g_nstart[ci] = acc; g_nend[ci] = acc + tot[k]; ++ci; }
                    acc += tot[k];
                }
                for (int c = ci; c < cbase + 8; ++c) g_nstart[c] = -1;
                g_nodes[n].meta = make_int4(st, en, cbase, nonempty);
                s_info = 1;
            }
        }
        __syncthreads();
    } else if (tid == 0) {
        for (int c = 0; c < 8; ++c) g_nstart[cbase + c] = -1;
    }

    if (s_info == 1) {
        const float cx = s_cc[0], cy = s_cc[1], cz = s_cc[2];
        for (int j = st + tid; j < en; j += 1024) {
            float x = pos[3*j], y = pos[3*j+1], z = pos[3*j+2], s = src[j];
            int oct = (x >= cx ? 1 : 0) | (y >= cy ? 2 : 0) | (z >= cz ? 4 : 0);
            int pdst = atomicAdd(&s_cur[oct], 1);
            g_p4[pdst] = make_float4(x, y, z, s);
            g_perm[pdst] = j;
        }
    } else {
        for (int j = st + tid; j < en; j += 1024) {
            g_p4[j] = make_float4(pos[3*j], pos[3*j+1], pos[3*j+2], src[j]);
            g_perm[j] = j;
        }
    }
}

// Level 1 (256 threads): iterate fixed arena, skip invalid slots.
__global__ __launch_bounds__(256) void level1_kernel()
{
    __shared__ NodeSh sh;
    const int lb = g_lrange[0], le = g_lrange[1];
    for (int n = lb + blockIdx.x; n < le; n += BGRID) {
        __syncthreads();
        int st = g_nstart[n];
        if (st < 0) continue;
        process_node2(sh, n, st, g_nend[n]);
    }
    __syncthreads();
    if (threadIdx.x == 0) {
        __threadfence();
        int d = atomicAdd(&g_done[1], 1);
        if (d == BGRID - 1)
            g_lrange[2] = atomicAdd(&g_ncount, 0);
    }
}

// ---------------------------------------------------------------------------
// LDS-resident subtree DFS (cnt <= LCAP) — R11-proven, AoS node writes.
// ---------------------------------------------------------------------------
__device__ __forceinline__ void lds_subtree(int rootn, int st, int en, int abase,
                                            float4* a4, int* aid,
                                            int* lid, int* la, int* lbb)
{
    const int lane = threadIdx.x & 63;
    const int cnt = en - st;
    const unsigned long long mlt = (1ull << lane) - 1ull;

    for (int j = lane; j < cnt; j += 64) {
        a4[j]  = g_p4[st + j];
        aid[j] = g_perm[st + j];
    }
    asm volatile("s_waitcnt vmcnt(0) lgkmcnt(0)" ::: "memory");
    __builtin_amdgcn_wave_barrier();

    int sp = 0;
    int cn = rootn, ca = 0, cb = cnt;
    while (true) {
        const int c = cb - ca;
        float4 pv[4]; int idv[4]; int oc[4];
        float mnx = 3.402823466e38f, mny = mnx, mnz = mnx;
        float mxx = -mnx, mxy = -mnx, mxz = -mnx;
        float sx = 0.f, sy = 0.f, sz = 0.f, sq = 0.f;
        #pragma unroll
        for (int i = 0; i < 4; ++i) {
            bool act = (i*64 + lane) < c;
            int j = act ? (ca + i*64 + lane) : ca;
            float4 p = a4[j];
            pv[i] = p; idv[i] = aid[j];
            if (act) {
                mnx = fminf(mnx, p.x); mny = fminf(mny, p.y); mnz = fminf(mnz, p.z);
                mxx = fmaxf(mxx, p.x); mxy = fmaxf(mxy, p.y); mxz = fmaxf(mxz, p.z);
                sx += p.x; sy += p.y; sz += p.z; sq += p.w;
            }
        }
        for (int o = 1; o < 64; o <<= 1) {
            mnx = fminf(mnx, __shfl_xor(mnx, o));
            mny = fminf(mny, __shfl_xor(mny, o));
            mnz = fminf(mnz, __shfl_xor(mnz, o));
            mxx = fmaxf(mxx, __shfl_xor(mxx, o));
            mxy = fmaxf(mxy, __shfl_xor(mxy, o));
            mxz = fmaxf(mxz, __shfl_xor(mxz, o));
            sx += __shfl_xor(sx, o);
            sy += __shfl_xor(sy, o);
            sz += __shfl_xor(sz, o);
            sq += __shfl_xor(sq, o);
        }
        const float cx = 0.5f * (mnx + mxx);
        const float cy = 0.5f * (mny + mxy);
        const float cz = 0.5f * (mnz + mxz);
        if (lane == 0) {
            g_nodes[cn].c4 = make_float4(cx, cy, cz, 0.5f * fmaxf(fmaxf(mxx - mnx, mxy - mny), mxz - mnz));
            const float fc = (float)c;
            g_nodes[cn].m4 = make_float4(sx / fc, sy / fc, sz / fc, sq);
        }

        int nonempty = 0;
        int c8[8] = {0,0,0,0,0,0,0,0};
        if (c > LEAF_SZ) {
            #pragma unroll
            for (int i = 0; i < 4; ++i) {
                bool act = (i*64 + lane) < c;
                int o = act ? ((pv[i].x >= cx ? 1 : 0) | (pv[i].y >= cy ? 2 : 0) | (pv[i].z >= cz ? 4 : 0)) : 8;
                oc[i] = o;
                #pragma unroll
                for (int k = 0; k < 8; ++k)
                    c8[k] += (int)__popcll(__ballot(o == k));
            }
            #pragma unroll
            for (int k = 0; k < 8; ++k) nonempty += (c8[k] > 0) ? 1 : 0;
        }

        if (c <= LEAF_SZ || nonempty <= 1) {
            if (lane == 0) g_nodes[cn].meta = make_int4(st + ca, st + cb, 0, 0);
        } else {
            int off[8], acc = 0;
            #pragma unroll
            for (int k = 0; k < 8; ++k) { off[k] = acc; acc += c8[k]; }
            if (lane == 0) g_nodes[cn].meta = make_int4(st + ca, st + cb, abase, nonempty);
            int cum[8] = {0,0,0,0,0,0,0,0};
            #pragma unroll
            for (int i = 0; i < 4; ++i) {
                int o = oc[i];
                int pdst = 0;
                #pragma unroll
                for (int k = 0; k < 8; ++k) {
                    unsigned long long b = __ballot(o == k);
                    if (o == k) pdst = ca + off[k] + cum[k] + (int)__popcll(b & mlt);
                    cum[k] += (int)__popcll(b);
                }
                if (o < 8) { a4[pdst] = pv[i]; aid[pdst] = idv[i]; }
            }
            asm volatile("s_waitcnt lgkmcnt(0)" ::: "memory");
            __builtin_amdgcn_wave_barrier();
            if (lane == 0) {
                int ci = 0;
                #pragma unroll
                for (int k = 0; k < 8; ++k) {
                    if (c8[k] > 0) {
                        lid[sp + ci] = abase + ci;
                        la [sp + ci] = ca + off[k];
                        lbb[sp + ci] = ca + off[k] + c8[k];
                        ++ci;
                    }
                }
            }
            abase += nonempty; sp += nonempty;
            if (sp > LSTK) sp = LSTK;
        }
        if (sp <= 0) break;
        --sp;
        __builtin_amdgcn_wave_barrier();
        asm volatile("s_waitcnt lgkmcnt(0)" ::: "memory");
        cn = lid[sp]; ca = la[sp]; cb = lbb[sp];
        __builtin_amdgcn_wave_barrier();
    }

    for (int j = lane; j < cnt; j += 64) {
        g_p4[st + j]  = a4[j];
        g_perm[st + j] = aid[j];
    }
    asm volatile("s_waitcnt vmcnt(0)" ::: "memory");
}

// ---------------------------------------------------------------------------
// Level-2+ build (R15-proven): block claims a frontier task; phase 1
// block-coop DFS over >LCAP nodes; phase 2 waves drain small subtrees.
// ---------------------------------------------------------------------------
__global__ __launch_bounds__(256) void block_subtree_kernel()
{
    __shared__ NodeSh sh;
    __shared__ int bs_id[BSTK], bs_st[BSTK], bs_en[BSTK];
    __shared__ int wq_id[WQCAP], wq_st[WQCAP], wq_en[WQCAP];
    __shared__ int s_bsp, s_wq;
    __shared__ float4 s_a4[4][LCAP];
    __shared__ int    s_aid[4][LCAP];
    __shared__ int    s_lid[4][LSTK], s_la[4][LSTK], s_lb[4][LSTK];

    const int tid = threadIdx.x;
    const int wid = tid >> 6;
    const int lb = g_lrange[1], le = g_lrange[2];

    for (int task = lb + blockIdx.x; task < le; task += BGRID) {
        __syncthreads();
        if (tid == 0) {
            int st = g_nstart[task], en = g_nend[task];
            if (en - st <= LCAP) { wq_id[0] = task; wq_st[0] = st; wq_en[0] = en; s_wq = 1; s_bsp = 0; }
            else                 { bs_id[0] = task; bs_st[0] = st; bs_en[0] = en; s_bsp = 1; s_wq = 0; }
        }
        __syncthreads();

        while (true) {
            __syncthreads();
            const int bsp = s_bsp;
            if (bsp == 0) break;
            const int n  = bs_id[bsp-1];
            const int st = bs_st[bsp-1];
            const int en = bs_en[bsp-1];
            __syncthreads();
            if (tid == 0) s_bsp = bsp - 1;
            process_node2(sh, n, st, en);
            if (tid == 0 && sh.info == 1) {
                int ci = 0;
                #pragma unroll
                for (int k = 0; k < 8; ++k) {
                    if (sh.tot[k] > 0) {
                        int cst = st + sh.offk[k], cen = cst + sh.tot[k];
                        int cid = sh.base + ci; ++ci;
                        if (cen - cst <= LCAP && s_wq < WQCAP) {
                            wq_id[s_wq] = cid; wq_st[s_wq] = cst; wq_en[s_wq] = cen; ++s_wq;
                        } else if (s_bsp < BSTK) {
                            bs_id[s_bsp] = cid; bs_st[s_bsp] = cst; bs_en[s_bsp] = cen; ++s_bsp;
                        }
                    }
                }
            }
        }
        __syncthreads();

        const int nwq = s_wq;
        float4* a4 = s_a4[wid];  int* aid = s_aid[wid];
        int* lid = s_lid[wid];   int* la = s_la[wid];  int* lbb = s_lb[wid];
        for (int i = wid; i < nwq; i += 4) {
            int cid = wq_id[i], cst = wq_st[i], cen = wq_en[i];
            lds_subtree(cid, cst, cen, ARENA_BASE + 2 * cst, a4, aid, lid, la, lbb);
        }
    }
}

// ---------------------------------------------------------------------------
// Traverse (R15 shape): 4 waves/block, one target per wave, static perm-order
// assignment (L1 sharing). Leaf pairs drained via shfl BINARY SEARCH over the
// non-decreasing per-lane offsets (no LDS, no waits) — owner(p) = max lane
// with off <= p; identical pair order to the proven scan version.
// ---------------------------------------------------------------------------
__global__ __launch_bounds__(256)
void traverse_kernel(const int* __restrict__ batch,
                     const float* __restrict__ p_scr, const float* __restrict__ p_soft,
                     float* __restrict__ out, int N)
{
    __shared__ int s_q[4][NQ];
    __shared__ int s_qt[4];
    const int wid  = threadIdx.x >> 6;
    const int lane = threadIdx.x & 63;
    const int slot = blockIdx.x * 4 + wid;
    if (slot >= N) return;                 // wave-uniform; no __syncthreads used
    const int t = g_perm[slot];

    const float scr   = p_scr[0];
    const float soft  = p_soft[0];
    const float soft2 = soft * soft;
    const float cexp  = -scr * 1.4426950408889634f;  // exp(-scr*r) = exp2(cexp*r)
    const float4 tp = g_p4[slot];
    const float tx = tp.x, ty = tp.y, tz = tp.z;
    const int inv_t = slot;

    volatile int* q = s_q[wid];
    if (lane == 0) { q[0] = g_root[batch[t]]; s_qt[wid] = 1; }
    __builtin_amdgcn_wave_barrier();

    float phi = 0.f;
    int qh = 0;
    while (true) {
        __builtin_amdgcn_wave_barrier();
        int qt = ((volatile int*)s_qt)[wid];
        if (qh >= qt) break;
        int take = qt - qh; if (take > 64) take = 64;
        int node = (lane < take) ? q[(qh + lane) & (NQ - 1)] : -1;
        qh += take;

        int leaf_st = 0, leaf_cnt = 0;
        if (node >= 0) {
            const int4 meta = g_nodes[node].meta;
            if (meta.w == 0) {
                leaf_st = meta.x; leaf_cnt = meta.y - meta.x;
            } else {
                float4 c4 = g_nodes[node].c4;
                float dx = tx - c4.x, dy = ty - c4.y, dz = tz - c4.z;
                float dist = sqrtf(dx*dx + dy*dy + dz*dz + soft2);
                float diam = fmaxf(2.0f * c4.w, 1e-9f);
                bool inside = (inv_t >= meta.x) && (inv_t < meta.y);
                if (!inside && diam < 0.5f * dist) {
                    float4 m4 = g_nodes[node].m4;
                    float ax = tx - m4.x, ay = ty - m4.y, az = tz - m4.z;
                    float s = ax*ax + ay*ay + az*az + soft2;
                    float rinv = rsqrtf(s);
                    phi += m4.w * exp2f(cexp * (s * rinv)) * rinv;
                } else {
                    int p = atomicAdd(&s_qt[wid], meta.w);
                    for (int c = 0; c < meta.w; ++c) q[(p + c) & (NQ - 1)] = meta.z + c;
                }
            }
        }

        // exclusive prefix-sum of (leaf size minus self) across lanes
        bool hasself = (inv_t >= leaf_st) && (inv_t < leaf_st + leaf_cnt);
        int cnt_adj = leaf_cnt - (hasself ? 1 : 0);
        int x = cnt_adj;
        #pragma unroll
        for (int o = 1; o < 64; o <<= 1) { int y = __shfl_up(x, o); if (lane >= o) x += y; }
        int total = __shfl(x, 63);
        int off = x - cnt_adj;

        if (total > 0) {
            const int sbv = leaf_st - off;                                   // owner base
            const int ssv = hasself ? (off + (inv_t - leaf_st)) : 0x7fffffff; // owner self-pos
            for (int cb = 0; cb < total; cb += 64) {
                int p = cb + lane;
                // owner(p) = max lane o with off_o <= p (off non-decreasing)
                int own = 0;
                #pragma unroll
                for (int stp = 32; stp >= 1; stp >>= 1) {
                    int cand = own + stp;
                    int oc = __shfl(off, cand & 63);
                    if (cand < 64 && oc <= p) own = cand;
                }
                int sbo = __shfl(sbv, own);
                int sso = __shfl(ssv, own);
                if (p < total) {
                    int j = sbo + p + ((p >= sso) ? 1 : 0);
                    float4 pp = g_p4[j];
                    float dx = tx - pp.x, dy = ty - pp.y, dz = tz - pp.z;
                    float s = dx*dx + dy*dy + dz*dz + soft2;
                    float rinv = rsqrtf(s);
                    phi += pp.w * exp2f(cexp * (s * rinv)) * rinv;
                }
            }
        }
    }

    #pragma unroll
    for (int o = 1; o < 64; o <<= 1) phi += __shfl_xor(phi, o);
    if (lane == 0) out[t] = 0.5f * (tp.w * phi);
}

extern "C" void kernel_launch(void* const* d_in, const int* in_sizes, int n_in,
                              void* d_out, int out_size, void* d_ws, size_t ws_size,
                              hipStream_t stream) {
    const float* pos    = (const float*)d_in[0];
    const int*   batch  = (const int*)  d_in[1];
    const float* source = (const float*)d_in[3];
    const float* p_scr  = (const float*)d_in[4];
    const float* p_soft = (const float*)d_in[5];

    const int N        = in_sizes[0] / 3;
    const int n_graphs = in_sizes[2] / 9;

    int g0 = n_graphs > 0 ? n_graphs : 1;
    if (g0 > MAXG) g0 = MAXG;
    level0_kernel<<<g0, 1024, 0, stream>>>(pos, source, batch, N, n_graphs);
    level1_kernel<<<BGRID, 256, 0, stream>>>();
    block_subtree_kernel<<<BGRID, 256, 0, stream>>>();

    const int blocks = (N + 3) / 4;  // 4 waves (targets) per 256-thread block
    traverse_kernel<<<blocks, 256, 0, stream>>>(batch, p_scr, p_soft, (float*)d_out, N);
}

// Round 22
// 143.337 us; speedup vs baseline: 1.5170x; 1.0212x over previous
//
#include <hip/hip_runtime.h>

#define LEAF_SZ 32
#define MAXN 16384
#define MAXNODES 65536
#define ARENA_BASE 32768
#define MAXG 64
#define NQ 1024
#define BGRID 128
#define LCAP 256
#define LSTK 192
#define BSTK 32
#define WQCAP 64
#define NW0 16

struct __align__(64) TNode { int4 meta; float4 c4; float4 m4; float4 pad; };

// Static device scratch (fully rewritten each call; no cross-call state relied on).
__device__ int    g_perm[MAXN];
__device__ int    g_ptmp[MAXN];
__device__ float4 g_p4[MAXN];    // x,y,z,charge in perm order
__device__ float4 g_t4[MAXN];
__device__ int    g_nstart[MAXNODES];
__device__ int    g_nend[MAXNODES];
__device__ TNode  g_nodes[MAXNODES];
__device__ int    g_root[MAXG];
__device__ int    g_ncount;
__device__ int    g_lrange[4];
__device__ int    g_done[2];

struct NodeSh {
    float  mn[4][3], mx[4][3];
    double sx[4], sy[4], sz[4], sq[4];
    int    c8[4][8];
    int    cur[8];
    float  cc[3];
    int    info;
    int    base, num;
    int    tot[8], offk[8];
};

// Block-cooperative node processing (R2-proven logic, 256 threads).
__device__ __forceinline__ void process_node2(NodeSh& sh, int n, int st, int en)
{
    const int tid  = threadIdx.x;
    const int wid  = tid >> 6;
    const int lane = tid & 63;
    const int cnt = en - st;

    float mnx = 3.402823466e38f, mny = mnx, mnz = mnx;
    float mxx = -mnx, mxy = -mnx, mxz = -mnx;
    double sx = 0.0, sy = 0.0, sz = 0.0, sq = 0.0;
    for (int j = st + tid; j < en; j += 256) {
        float4 p = g_p4[j];
        mnx = fminf(mnx, p.x); mny = fminf(mny, p.y); mnz = fminf(mnz, p.z);
        mxx = fmaxf(mxx, p.x); mxy = fmaxf(mxy, p.y); mxz = fmaxf(mxz, p.z);
        sx += (double)p.x; sy += (double)p.y; sz += (double)p.z; sq += (double)p.w;
    }
    for (int o = 1; o < 64; o <<= 1) {
        mnx = fminf(mnx, __shfl_xor(mnx, o));
        mny = fminf(mny, __shfl_xor(mny, o));
        mnz = fminf(mnz, __shfl_xor(mnz, o));
        mxx = fmaxf(mxx, __shfl_xor(mxx, o));
        mxy = fmaxf(mxy, __shfl_xor(mxy, o));
        mxz = fmaxf(mxz, __shfl_xor(mxz, o));
        sx += __shfl_xor(sx, o);
        sy += __shfl_xor(sy, o);
        sz += __shfl_xor(sz, o);
        sq += __shfl_xor(sq, o);
    }
    if (lane == 0) {
        sh.mn[wid][0] = mnx; sh.mn[wid][1] = mny; sh.mn[wid][2] = mnz;
        sh.mx[wid][0] = mxx; sh.mx[wid][1] = mxy; sh.mx[wid][2] = mxz;
        sh.sx[wid] = sx; sh.sy[wid] = sy; sh.sz[wid] = sz; sh.sq[wid] = sq;
    }
    __syncthreads();
    if (tid == 0) {
        float a0 = sh.mn[0][0], a1 = sh.mn[0][1], a2 = sh.mn[0][2];
        float b0 = sh.mx[0][0], b1 = sh.mx[0][1], b2 = sh.mx[0][2];
        double tx = sh.sx[0], ty = sh.sy[0], tz = sh.sz[0], tq = sh.sq[0];
        for (int w = 1; w < 4; ++w) {
            a0 = fminf(a0, sh.mn[w][0]); a1 = fminf(a1, sh.mn[w][1]); a2 = fminf(a2, sh.mn[w][2]);
            b0 = fmaxf(b0, sh.mx[w][0]); b1 = fmaxf(b1, sh.mx[w][1]); b2 = fmaxf(b2, sh.mx[w][2]);
            tx += sh.sx[w]; ty += sh.sy[w]; tz += sh.sz[w]; tq += sh.sq[w];
        }
        float cx = 0.5f * (a0 + b0), cy = 0.5f * (a1 + b1), cz = 0.5f * (a2 + b2);
        g_nodes[n].c4 = make_float4(cx, cy, cz, 0.5f * fmaxf(fmaxf(b0 - a0, b1 - a1), b2 - a2));
        const float fc = (float)cnt;
        g_nodes[n].m4 = make_float4((float)tx / fc, (float)ty / fc, (float)tz / fc, (float)tq);
        sh.cc[0] = cx; sh.cc[1] = cy; sh.cc[2] = cz;
        if (cnt <= LEAF_SZ) { g_nodes[n].meta = make_int4(st, en, 0, 0); sh.info = -1; }
        else sh.info = 0;
    }
    __syncthreads();
    if (sh.info < 0) return;
    const float cx = sh.cc[0], cy = sh.cc[1], cz = sh.cc[2];

    int c8[8] = {0,0,0,0,0,0,0,0};
    for (int j = st + tid; j < en; j += 256) {
        float4 p = g_p4[j];
        int oct = (p.x >= cx ? 1 : 0) | (p.y >= cy ? 2 : 0) | (p.z >= cz ? 4 : 0);
        c8[oct]++;
    }
    #pragma unroll
    for (int k = 0; k < 8; ++k)
        for (int o = 1; o < 64; o <<= 1)
            c8[k] += __shfl_xor(c8[k], o);
    if (lane == 0)
        #pragma unroll
        for (int k = 0; k < 8; ++k) sh.c8[wid][k] = c8[k];
    __syncthreads();
    if (tid == 0) {
        int tot[8], nonempty = 0;
        #pragma unroll
        for (int k = 0; k < 8; ++k) {
            tot[k] = sh.c8[0][k] + sh.c8[1][k] + sh.c8[2][k] + sh.c8[3][k];
            nonempty += (tot[k] > 0) ? 1 : 0;
        }
        if (nonempty <= 1) { g_nodes[n].meta = make_int4(st, en, 0, 0); sh.info = -1; }
        else {
            int base = atomicAdd(&g_ncount, nonempty);
            int acc = st, ci = base;
            #pragma unroll
            for (int k = 0; k < 8; ++k) {
                sh.cur[k] = acc;
                sh.offk[k] = acc - st;
                sh.tot[k] = tot[k];
                if (tot[k] > 0) { g_nstart[ci] = acc; g_nend[ci] = acc + tot[k]; ++ci; }
                acc += tot[k];
            }
            g_nodes[n].meta = make_int4(st, en, base, nonempty);
            sh.base = base; sh.num = nonempty; sh.info = 1;
        }
    }
    __syncthreads();
    if (sh.info < 0) return;

    for (int j = st + tid; j < en; j += 256) {
        float4 p = g_p4[j];
        int id = g_perm[j];
        int oct = (p.x >= cx ? 1 : 0) | (p.y >= cy ? 2 : 0) | (p.z >= cz ? 4 : 0);
        int pdst = atomicAdd(&sh.cur[oct], 1);
        g_ptmp[pdst] = id; g_t4[pdst] = p;
    }
    __syncthreads();
    for (int j = st + tid; j < en; j += 256) {
        g_perm[j] = g_ptmp[j];
        g_p4[j]   = g_t4[j];
    }
    __syncthreads();
}

// ---------------------------------------------------------------------------
// Fused init + level-0 (R15-proven): one 1024-thread block per graph, reading
// inputs directly; fixed child arena (nc + g*8, unused slots -1).
// ---------------------------------------------------------------------------
__global__ __launch_bounds__(1024)
void level0_kernel(const float* __restrict__ pos, const float* __restrict__ src,
                   const int* __restrict__ batch, int N, int n_graphs)
{
    __shared__ int    s_first[MAXG], s_end[MAXG];
    __shared__ float  s_mn[NW0][3], s_mx[NW0][3];
    __shared__ double s_sx[NW0], s_sy[NW0], s_sz[NW0], s_sq[NW0];
    __shared__ int    s_c8[NW0][8];
    __shared__ int    s_cur[8];
    __shared__ float  s_cc[3];
    __shared__ int    s_info;
    const int tid = threadIdx.x, wid = tid >> 6, lane = tid & 63;
    const int ng = (n_graphs < MAXG) ? n_graphs : MAXG;

    for (int g = tid; g < MAXG; g += 1024) { s_first[g] = -1; s_end[g] = 0; }
    __syncthreads();
    for (int i = tid; i < N; i += 1024) {
        int b = batch[i];
        if (i == 0     || batch[i-1] != b) s_first[b] = i;
        if (i == N - 1 || batch[i+1] != b) s_end[b]   = i + 1;
    }
    __syncthreads();

    const int g = blockIdx.x;
    int nc = 0, myroot = -1;
    for (int q = 0; q < ng; ++q)
        if (s_first[q] >= 0) { if (q == g) myroot = nc; ++nc; }
    const int nb = nc + 8 * ng;

    if (g == 0 && tid == 0) {
        int r = 0;
        for (int q = 0; q < ng; ++q) {
            if (s_first[q] >= 0) g_root[q] = r++;
            else {
                g_root[q] = -1;
                for (int c = 0; c < 8; ++c) g_nstart[nc + q*8 + c] = -1;  // dead arena
            }
        }
        g_ncount = nb;
        g_lrange[0] = nc;
        g_lrange[1] = nb;
        g_done[1] = 0;
    }
    if (g >= ng || myroot < 0) return;

    const int st = s_first[g], en = s_end[g];
    const int cnt = en - st;
    const int n = myroot;
    const int cbase = nc + g * 8;

    float mnx = 3.402823466e38f, mny = mnx, mnz = mnx;
    float mxx = -mnx, mxy = -mnx, mxz = -mnx;
    double sx = 0.0, sy = 0.0, sz = 0.0, sq = 0.0;
    for (int j = st + tid; j < en; j += 1024) {
        float x = pos[3*j], y = pos[3*j+1], z = pos[3*j+2], s = src[j];
        mnx = fminf(mnx, x); mny = fminf(mny, y); mnz = fminf(mnz, z);
        mxx = fmaxf(mxx, x); mxy = fmaxf(mxy, y); mxz = fmaxf(mxz, z);
        sx += (double)x; sy += (double)y; sz += (double)z; sq += (double)s;
    }
    for (int o = 1; o < 64; o <<= 1) {
        mnx = fminf(mnx, __shfl_xor(mnx, o));
        mny = fminf(mny, __shfl_xor(mny, o));
        mnz = fminf(mnz, __shfl_xor(mnz, o));
        mxx = fmaxf(mxx, __shfl_xor(mxx, o));
        mxy = fmaxf(mxy, __shfl_xor(mxy, o));
        mxz = fmaxf(mxz, __shfl_xor(mxz, o));
        sx += __shfl_xor(sx, o);
        sy += __shfl_xor(sy, o);
        sz += __shfl_xor(sz, o);
        sq += __shfl_xor(sq, o);
    }
    if (lane == 0) {
        s_mn[wid][0] = mnx; s_mn[wid][1] = mny; s_mn[wid][2] = mnz;
        s_mx[wid][0] = mxx; s_mx[wid][1] = mxy; s_mx[wid][2] = mxz;
        s_sx[wid] = sx; s_sy[wid] = sy; s_sz[wid] = sz; s_sq[wid] = sq;
    }
    __syncthreads();
    if (tid == 0) {
        float a0 = s_mn[0][0], a1 = s_mn[0][1], a2 = s_mn[0][2];
        float b0 = s_mx[0][0], b1 = s_mx[0][1], b2 = s_mx[0][2];
        double tx = s_sx[0], ty = s_sy[0], tz = s_sz[0], tq = s_sq[0];
        for (int w = 1; w < NW0; ++w) {
            a0 = fminf(a0, s_mn[w][0]); a1 = fminf(a1, s_mn[w][1]); a2 = fminf(a2, s_mn[w][2]);
            b0 = fmaxf(b0, s_mx[w][0]); b1 = fmaxf(b1, s_mx[w][1]); b2 = fmaxf(b2, s_mx[w][2]);
            tx += s_sx[w]; ty += s_sy[w]; tz += s_sz[w]; tq += s_sq[w];
        }
        float cx = 0.5f * (a0 + b0), cy = 0.5f * (a1 + b1), cz = 0.5f * (a2 + b2);
        g_nodes[n].c4 = make_float4(cx, cy, cz, 0.5f * fmaxf(fmaxf(b0 - a0, b1 - a1), b2 - a2));
        const float fc = (float)cnt;
        g_nodes[n].m4 = make_float4((float)tx / fc, (float)ty / fc, (float)tz / fc, (float)tq);
        s_cc[0] = cx; s_cc[1] = cy; s_cc[2] = cz;
        s_info = (cnt <= LEAF_SZ) ? -1 : 0;
        if (s_info < 0) g_nodes[n].meta = make_int4(st, en, 0, 0);
    }
    __syncthreads();

    if (s_info == 0) {
        const float cx = s_cc[0], cy = s_cc[1], cz = s_cc[2];
        int c8[8] = {0,0,0,0,0,0,0,0};
        for (int j = st + tid; j < en; j += 1024) {
            int oct = (pos[3*j] >= cx ? 1 : 0) | (pos[3*j+1] >= cy ? 2 : 0) | (pos[3*j+2] >= cz ? 4 : 0);
            c8[oct]++;
        }
        #pragma unroll
        for (int k = 0; k < 8; ++k)
            for (int o = 1; o < 64; o <<= 1)
                c8[k] += __shfl_xor(c8[k], o);
        if (lane == 0)
            #pragma unroll
            for (int k = 0; k < 8; ++k) s_c8[wid][k] = c8[k];
        __syncthreads();
        if (tid == 0) {
            int tot[8], nonempty = 0;
            #pragma unroll
            for (int k = 0; k < 8; ++k) {
                int tk = 0;
                for (int w = 0; w < NW0; ++w) tk += s_c8[w][k];
                tot[k] = tk;
                nonempty += (tk > 0) ? 1 : 0;
            }
            if (nonempty <= 1) {
                g_nodes[n].meta = make_int4(st, en, 0, 0);
                for (int c = 0; c < 8; ++c) g_nstart[cbase + c] = -1;
                s_info = -1;
            } else {
                int acc = st, ci = cbase;
                #pragma unroll
                for (int k = 0; k < 8; ++k) {
                    s_cur[k] = acc;
                    if (tot[k] > 0) { g_nstart[ci] = acc; g_nend[ci] = acc + tot[k]; ++ci; }
                    acc += tot[k];
                }
                for (int c = ci; c < cbase + 8; ++c) g_nstart[c] = -1;
                g_nodes[n].meta = make_int4(st, en, cbase, nonempty);
                s_info = 1;
            }
        }
        __syncthreads();
    } else if (tid == 0) {
        for (int c = 0; c < 8; ++c) g_nstart[cbase + c] = -1;
    }

    if (s_info == 1) {
        const float cx = s_cc[0], cy = s_cc[1], cz = s_cc[2];
        for (int j = st + tid; j < en; j += 1024) {
            float x = pos[3*j], y = pos[3*j+1], z = pos[3*j+2], s = src[j];
            int oct = (x >= cx ? 1 : 0) | (y >= cy ? 2 : 0) | (z >= cz ? 4 : 0);
            int pdst = atomicAdd(&s_cur[oct], 1);
            g_p4[pdst] = make_float4(x, y, z, s);
            g_perm[pdst] = j;
        }
    } else {
        for (int j = st + tid; j < en; j += 1024) {
            g_p4[j] = make_float4(pos[3*j], pos[3*j+1], pos[3*j+2], src[j]);
            g_perm[j] = j;
        }
    }
}

// Level 1 (256 threads): iterate fixed arena, skip invalid slots.
__global__ __launch_bounds__(256) void level1_kernel()
{
    __shared__ NodeSh sh;
    const int lb = g_lrange[0], le = g_lrange[1];
    for (int n = lb + blockIdx.x; n < le; n += BGRID) {
        __syncthreads();
        int st = g_nstart[n];
        if (st < 0) continue;
        process_node2(sh, n, st, g_nend[n]);
    }
    __syncthreads();
    if (threadIdx.x == 0) {
        __threadfence();
        int d = atomicAdd(&g_done[1], 1);
        if (d == BGRID - 1)
            g_lrange[2] = atomicAdd(&g_ncount, 0);
    }
}

// ---------------------------------------------------------------------------
// LDS-resident subtree DFS (cnt <= LCAP) — R11-proven, AoS node writes.
// ---------------------------------------------------------------------------
__device__ __forceinline__ void lds_subtree(int rootn, int st, int en, int abase,
                                            float4* a4, int* aid,
                                            int* lid, int* la, int* lbb)
{
    const int lane = threadIdx.x & 63;
    const int cnt = en - st;
    const unsigned long long mlt = (1ull << lane) - 1ull;

    for (int j = lane; j < cnt; j += 64) {
        a4[j]  = g_p4[st + j];
        aid[j] = g_perm[st + j];
    }
    asm volatile("s_waitcnt vmcnt(0) lgkmcnt(0)" ::: "memory");
    __builtin_amdgcn_wave_barrier();

    int sp = 0;
    int cn = rootn, ca = 0, cb = cnt;
    while (true) {
        const int c = cb - ca;
        float4 pv[4]; int idv[4]; int oc[4];
        float mnx = 3.402823466e38f, mny = mnx, mnz = mnx;
        float mxx = -mnx, mxy = -mnx, mxz = -mnx;
        float sx = 0.f, sy = 0.f, sz = 0.f, sq = 0.f;
        #pragma unroll
        for (int i = 0; i < 4; ++i) {
            bool act = (i*64 + lane) < c;
            int j = act ? (ca + i*64 + lane) : ca;
            float4 p = a4[j];
            pv[i] = p; idv[i] = aid[j];
            if (act) {
                mnx = fminf(mnx, p.x); mny = fminf(mny, p.y); mnz = fminf(mnz, p.z);
                mxx = fmaxf(mxx, p.x); mxy = fmaxf(mxy, p.y); mxz = fmaxf(mxz, p.z);
                sx += p.x; sy += p.y; sz += p.z; sq += p.w;
            }
        }
        for (int o = 1; o < 64; o <<= 1) {
            mnx = fminf(mnx, __shfl_xor(mnx, o));
            mny = fminf(mny, __shfl_xor(mny, o));
            mnz = fminf(mnz, __shfl_xor(mnz, o));
            mxx = fmaxf(mxx, __shfl_xor(mxx, o));
            mxy = fmaxf(mxy, __shfl_xor(mxy, o));
            mxz = fmaxf(mxz, __shfl_xor(mxz, o));
            sx += __shfl_xor(sx, o);
            sy += __shfl_xor(sy, o);
            sz += __shfl_xor(sz, o);
            sq += __shfl_xor(sq, o);
        }
        const float cx = 0.5f * (mnx + mxx);
        const float cy = 0.5f * (mny + mxy);
        const float cz = 0.5f * (mnz + mxz);
        if (lane == 0) {
            g_nodes[cn].c4 = make_float4(cx, cy, cz, 0.5f * fmaxf(fmaxf(mxx - mnx, mxy - mny), mxz - mnz));
            const float fc = (float)c;
            g_nodes[cn].m4 = make_float4(sx / fc, sy / fc, sz / fc, sq);
        }

        int nonempty = 0;
        int c8[8] = {0,0,0,0,0,0,0,0};
        if (c > LEAF_SZ) {
            #pragma unroll
            for (int i = 0; i < 4; ++i) {
                bool act = (i*64 + lane) < c;
                int o = act ? ((pv[i].x >= cx ? 1 : 0) | (pv[i].y >= cy ? 2 : 0) | (pv[i].z >= cz ? 4 : 0)) : 8;
                oc[i] = o;
                #pragma unroll
                for (int k = 0; k < 8; ++k)
                    c8[k] += (int)__popcll(__ballot(o == k));
            }
            #pragma unroll
            for (int k = 0; k < 8; ++k) nonempty += (c8[k] > 0) ? 1 : 0;
        }

        if (c <= LEAF_SZ || nonempty <= 1) {
            if (lane == 0) g_nodes[cn].meta = make_int4(st + ca, st + cb, 0, 0);
        } else {
            int off[8], acc = 0;
            #pragma unroll
            for (int k = 0; k < 8; ++k) { off[k] = acc; acc += c8[k]; }
            if (lane == 0) g_nodes[cn].meta = make_int4(st + ca, st + cb, abase, nonempty);
            int cum[8] = {0,0,0,0,0,0,0,0};
            #pragma unroll
            for (int i = 0; i < 4; ++i) {
                int o = oc[i];
                int pdst = 0;
                #pragma unroll
                for (int k = 0; k < 8; ++k) {
                    unsigned long long b = __ballot(o == k);
                    if (o == k) pdst = ca + off[k] + cum[k] + (int)__popcll(b & mlt);
                    cum[k] += (int)__popcll(b);
                }
                if (o < 8) { a4[pdst] = pv[i]; aid[pdst] = idv[i]; }
            }
            asm volatile("s_waitcnt lgkmcnt(0)" ::: "memory");
            __builtin_amdgcn_wave_barrier();
            if (lane == 0) {
                int ci = 0;
                #pragma unroll
                for (int k = 0; k < 8; ++k) {
                    if (c8[k] > 0) {
                        lid[sp + ci] = abase + ci;
                        la [sp + ci] = ca + off[k];
                        lbb[sp + ci] = ca + off[k] + c8[k];
                        ++ci;
                    }
                }
            }
            abase += nonempty; sp += nonempty;
            if (sp > LSTK) sp = LSTK;
        }
        if (sp <= 0) break;
        --sp;
        __builtin_amdgcn_wave_barrier();
        asm volatile("s_waitcnt lgkmcnt(0)" ::: "memory");
        cn = lid[sp]; ca = la[sp]; cb = lbb[sp];
        __builtin_amdgcn_wave_barrier();
    }

    for (int j = lane; j < cnt; j += 64) {
        g_p4[st + j]  = a4[j];
        g_perm[st + j] = aid[j];
    }
    asm volatile("s_waitcnt vmcnt(0)" ::: "memory");
}

// ---------------------------------------------------------------------------
// Level-2+ build (R15-proven): block claims a frontier task; phase 1
// block-coop DFS over >LCAP nodes; phase 2 waves drain small subtrees.
// ---------------------------------------------------------------------------
__global__ __launch_bounds__(256) void block_subtree_kernel()
{
    __shared__ NodeSh sh;
    __shared__ int bs_id[BSTK], bs_st[BSTK], bs_en[BSTK];
    __shared__ int wq_id[WQCAP], wq_st[WQCAP], wq_en[WQCAP];
    __shared__ int s_bsp, s_wq;
    __shared__ float4 s_a4[4][LCAP];
    __shared__ int    s_aid[4][LCAP];
    __shared__ int    s_lid[4][LSTK], s_la[4][LSTK], s_lb[4][LSTK];

    const int tid = threadIdx.x;
    const int wid = tid >> 6;
    const int lb = g_lrange[1], le = g_lrange[2];

    for (int task = lb + blockIdx.x; task < le; task += BGRID) {
        __syncthreads();
        if (tid == 0) {
            int st = g_nstart[task], en = g_nend[task];
            if (en - st <= LCAP) { wq_id[0] = task; wq_st[0] = st; wq_en[0] = en; s_wq = 1; s_bsp = 0; }
            else                 { bs_id[0] = task; bs_st[0] = st; bs_en[0] = en; s_bsp = 1; s_wq = 0; }
        }
        __syncthreads();

        while (true) {
            __syncthreads();
            const int bsp = s_bsp;
            if (bsp == 0) break;
            const int n  = bs_id[bsp-1];
            const int st = bs_st[bsp-1];
            const int en = bs_en[bsp-1];
            __syncthreads();
            if (tid == 0) s_bsp = bsp - 1;
            process_node2(sh, n, st, en);
            if (tid == 0 && sh.info == 1) {
                int ci = 0;
                #pragma unroll
                for (int k = 0; k < 8; ++k) {
                    if (sh.tot[k] > 0) {
                        int cst = st + sh.offk[k], cen = cst + sh.tot[k];
                        int cid = sh.base + ci; ++ci;
                        if (cen - cst <= LCAP && s_wq < WQCAP) {
                            wq_id[s_wq] = cid; wq_st[s_wq] = cst; wq_en[s_wq] = cen; ++s_wq;
                        } else if (s_bsp < BSTK) {
                            bs_id[s_bsp] = cid; bs_st[s_bsp] = cst; bs_en[s_bsp] = cen; ++s_bsp;
                        }
                    }
                }
            }
        }
        __syncthreads();

        const int nwq = s_wq;
        float4* a4 = s_a4[wid];  int* aid = s_aid[wid];
        int* lid = s_lid[wid];   int* la = s_la[wid];  int* lbb = s_lb[wid];
        for (int i = wid; i < nwq; i += 4) {
            int cid = wq_id[i], cst = wq_st[i], cen = wq_en[i];
            lds_subtree(cid, cst, cen, ARENA_BASE + 2 * cst, a4, aid, lid, la, lbb);
        }
    }
}

// ---------------------------------------------------------------------------
// Traverse: 4 waves/block; MIRROR-PAIR target assignment (front pair + back
// pair per block) flattens the heavy-core cost clustering while keeping
// adjacent-target L1 sharing. Leaf drain: empty-skip, single-owner fast path,
// shfl binary search otherwise. Identical per-target arithmetic order.
// ---------------------------------------------------------------------------
__global__ __launch_bounds__(256)
void traverse_kernel(const int* __restrict__ batch,
                     const float* __restrict__ p_scr, const float* __restrict__ p_soft,
                     float* __restrict__ out, int N)
{
    __shared__ int s_q[4][NQ];
    __shared__ int s_qt[4];
    const int wid  = threadIdx.x >> 6;
    const int lane = threadIdx.x & 63;
    int slot;
    if ((N & 3) == 0) {
        // block b: slots {2b, 2b+1, N-2-2b, N-1-2b}  (bijective for N%4==0)
        slot = (wid < 2) ? (2 * blockIdx.x + wid)
                         : (N - 2 - 2 * blockIdx.x + (wid - 2));
    } else {
        slot = blockIdx.x * 4 + wid;
    }
    if (slot < 0 || slot >= N) return;     // wave-uniform; no __syncthreads used
    const int t = g_perm[slot];

    const float scr   = p_scr[0];
    const float soft  = p_soft[0];
    const float soft2 = soft * soft;
    const float cexp  = -scr * 1.4426950408889634f;  // exp(-scr*r) = exp2(cexp*r)
    const float4 tp = g_p4[slot];
    const float tx = tp.x, ty = tp.y, tz = tp.z;
    const int inv_t = slot;

    volatile int* q = s_q[wid];
    if (lane == 0) { q[0] = g_root[batch[t]]; s_qt[wid] = 1; }
    __builtin_amdgcn_wave_barrier();

    float phi = 0.f;
    int qh = 0;
    while (true) {
        __builtin_amdgcn_wave_barrier();
        int qt = ((volatile int*)s_qt)[wid];
        if (qh >= qt) break;
        int take = qt - qh; if (take > 64) take = 64;
        int node = (lane < take) ? q[(qh + lane) & (NQ - 1)] : -1;
        qh += take;

        int leaf_st = 0, leaf_cnt = 0;
        if (node >= 0) {
            const int4 meta = g_nodes[node].meta;
            if (meta.w == 0) {
                leaf_st = meta.x; leaf_cnt = meta.y - meta.x;
            } else {
                float4 c4 = g_nodes[node].c4;
                float dx = tx - c4.x, dy = ty - c4.y, dz = tz - c4.z;
                float dist = sqrtf(dx*dx + dy*dy + dz*dz + soft2);
                float diam = fmaxf(2.0f * c4.w, 1e-9f);
                bool inside = (inv_t >= meta.x) && (inv_t < meta.y);
                if (!inside && diam < 0.5f * dist) {
                    float4 m4 = g_nodes[node].m4;
                    float ax = tx - m4.x, ay = ty - m4.y, az = tz - m4.z;
                    float s = ax*ax + ay*ay + az*az + soft2;
                    float rinv = rsqrtf(s);
                    phi += m4.w * exp2f(cexp * (s * rinv)) * rinv;
                } else {
                    int p = atomicAdd(&s_qt[wid], meta.w);
                    for (int c = 0; c < meta.w; ++c) q[(p + c) & (NQ - 1)] = meta.z + c;
                }
            }
        }

        bool hasself = (inv_t >= leaf_st) && (inv_t < leaf_st + leaf_cnt);
        int cnt_adj = leaf_cnt - (hasself ? 1 : 0);

        unsigned long long anyleaf = __ballot(cnt_adj > 0);
        if (anyleaf == 0ull) continue;                  // no leaf work this batch

        if (__popcll(anyleaf) == 1) {
            // single owner: base/selfpos/total via 3 shfls, no prefix/search
            const int solo  = (int)__builtin_ctzll(anyleaf);
            const int total = __shfl(cnt_adj, solo);
            const int sbo   = __shfl(leaf_st, solo);
            const int sso   = __shfl(hasself ? (inv_t - leaf_st) : 0x7fffffff, solo);
            for (int cb = 0; cb < total; cb += 64) {
                int p = cb + lane;
                if (p < total) {
                    int j = sbo + p + ((p >= sso) ? 1 : 0);
                    float4 pp = g_p4[j];
                    float dx = tx - pp.x, dy = ty - pp.y, dz = tz - pp.z;
                    float s = dx*dx + dy*dy + dz*dz + soft2;
                    float rinv = rsqrtf(s);
                    phi += pp.w * exp2f(cexp * (s * rinv)) * rinv;
                }
            }
        } else {
            // exclusive prefix-sum across lanes + shfl binary search for owner
            int x = cnt_adj;
            #pragma unroll
            for (int o = 1; o < 64; o <<= 1) { int y = __shfl_up(x, o); if (lane >= o) x += y; }
            int total = __shfl(x, 63);
            int off = x - cnt_adj;
            const int sbv = leaf_st - off;
            const int ssv = hasself ? (off + (inv_t - leaf_st)) : 0x7fffffff;
            for (int cb = 0; cb < total; cb += 64) {
                int p = cb + lane;
                int own = 0;
                #pragma unroll
                for (int stp = 32; stp >= 1; stp >>= 1) {
                    int cand = own + stp;
                    int oc = __shfl(off, cand & 63);
                    if (cand < 64 && oc <= p) own = cand;
                }
                int sbo = __shfl(sbv, own);
                int sso = __shfl(ssv, own);
                if (p < total) {
                    int j = sbo + p + ((p >= sso) ? 1 : 0);
                    float4 pp = g_p4[j];
                    float dx = tx - pp.x, dy = ty - pp.y, dz = tz - pp.z;
                    float s = dx*dx + dy*dy + dz*dz + soft2;
                    float rinv = rsqrtf(s);
                    phi += pp.w * exp2f(cexp * (s * rinv)) * rinv;
                }
            }
        }
    }

    #pragma unroll
    for (int o = 1; o < 64; o <<= 1) phi += __shfl_xor(phi, o);
    if (lane == 0) out[t] = 0.5f * (tp.w * phi);
}

extern "C" void kernel_launch(void* const* d_in, const int* in_sizes, int n_in,
                              void* d_out, int out_size, void* d_ws, size_t ws_size,
                              hipStream_t stream) {
    const float* pos    = (const float*)d_in[0];
    const int*   batch  = (const int*)  d_in[1];
    const float* source = (const float*)d_in[3];
    const float* p_scr  = (const float*)d_in[4];
    const float* p_soft = (const float*)d_in[5];

    const int N        = in_sizes[0] / 3;
    const int n_graphs = in_sizes[2] / 9;

    int g0 = n_graphs > 0 ? n_graphs : 1;
    if (g0 > MAXG) g0 = MAXG;
    level0_kernel<<<g0, 1024, 0, stream>>>(pos, source, batch, N, n_graphs);
    level1_kernel<<<BGRID, 256, 0, stream>>>();
    block_subtree_kernel<<<BGRID, 256, 0, stream>>>();

    const int blocks = (N + 3) / 4;  // 4 waves (targets) per 256-thread block
    traverse_kernel<<<blocks, 256, 0, stream>>>(batch, p_scr, p_soft, (float*)d_out, N);
}